// Round 1
// baseline (98.381 us; speedup 1.0000x reference)
//
#include <hip/hip_runtime.h>

// HistogramEqualization: reference collapses to out = x * hist[1]/(N - hist[0])
// because jnp.interp(x in [0,1], arange(256), cdfn) only uses cdfn[0..1] and
// cdfn[0] == 0 (cdf.min() == cdf[0]).
//
// Kernel 1: count bin0 (x < 1/256) and bin1 (1/256 <= x < 2/256) exactly.
// Kernel 2: scale elementwise.

__global__ __launch_bounds__(256) void histeq_count(const float4* __restrict__ x4,
                                                    unsigned int* __restrict__ cnt,
                                                    int n4, const float* __restrict__ x,
                                                    int n) {
    unsigned int c0 = 0, c1 = 0;
    int stride = gridDim.x * blockDim.x;
    for (int i = blockIdx.x * blockDim.x + threadIdx.x; i < n4; i += stride) {
        float4 v = x4[i];
        // (int)(v*256.0f) is exact for v in [0,1]: *256 is an exponent shift.
        int b0 = (int)(v.x * 256.0f);
        int b1 = (int)(v.y * 256.0f);
        int b2 = (int)(v.z * 256.0f);
        int b3 = (int)(v.w * 256.0f);
        c0 += (unsigned)(b0 == 0) + (unsigned)(b1 == 0) + (unsigned)(b2 == 0) + (unsigned)(b3 == 0);
        c1 += (unsigned)(b0 == 1) + (unsigned)(b1 == 1) + (unsigned)(b2 == 1) + (unsigned)(b3 == 1);
    }
    // scalar tail (n not multiple of 4) handled by one thread
    if (blockIdx.x == 0 && threadIdx.x == 0) {
        for (int i = n4 * 4; i < n; ++i) {
            int b = (int)(x[i] * 256.0f);
            c0 += (unsigned)(b == 0);
            c1 += (unsigned)(b == 1);
        }
    }
    // wave-64 butterfly reduce
#pragma unroll
    for (int off = 32; off > 0; off >>= 1) {
        c0 += __shfl_down(c0, off, 64);
        c1 += __shfl_down(c1, off, 64);
    }
    __shared__ unsigned int sm0[4], sm1[4];
    int lane = threadIdx.x & 63;
    int wid = threadIdx.x >> 6;
    if (lane == 0) { sm0[wid] = c0; sm1[wid] = c1; }
    __syncthreads();
    if (threadIdx.x == 0) {
        unsigned int t0 = sm0[0] + sm0[1] + sm0[2] + sm0[3];
        unsigned int t1 = sm1[0] + sm1[1] + sm1[2] + sm1[3];
        atomicAdd(&cnt[0], t0);
        atomicAdd(&cnt[1], t1);
    }
}

__global__ __launch_bounds__(256) void histeq_apply(const float4* __restrict__ x4,
                                                    float4* __restrict__ out4,
                                                    const unsigned int* __restrict__ cnt,
                                                    int n4, int n_total,
                                                    const float* __restrict__ x,
                                                    float* __restrict__ out) {
    __shared__ float s_scale;
    if (threadIdx.x == 0) {
        double h0 = (double)cnt[0];
        double h1 = (double)cnt[1];
        s_scale = (float)(h1 / ((double)n_total - h0));
    }
    __syncthreads();
    float s = s_scale;
    int stride = gridDim.x * blockDim.x;
    for (int i = blockIdx.x * blockDim.x + threadIdx.x; i < n4; i += stride) {
        float4 v = x4[i];
        float4 o;
        o.x = v.x * s;
        o.y = v.y * s;
        o.z = v.z * s;
        o.w = v.w * s;
        out4[i] = o;
    }
    if (blockIdx.x == 0 && threadIdx.x == 0) {
        for (int i = n4 * 4; i < n_total; ++i) out[i] = x[i] * s;
    }
}

extern "C" void kernel_launch(void* const* d_in, const int* in_sizes, int n_in,
                              void* d_out, int out_size, void* d_ws, size_t ws_size,
                              hipStream_t stream) {
    const float* x = (const float*)d_in[0];
    float* out = (float*)d_out;
    int n = in_sizes[0];
    int n4 = n >> 2;
    unsigned int* cnt = (unsigned int*)d_ws;

    hipMemsetAsync(cnt, 0, 2 * sizeof(unsigned int), stream);

    const int block = 256;
    int grid = 2048;
    int need = (n4 + block - 1) / block;
    if (grid > need) grid = need;
    if (grid < 1) grid = 1;

    histeq_count<<<grid, block, 0, stream>>>((const float4*)x, cnt, n4, x, n);
    histeq_apply<<<grid, block, 0, stream>>>((const float4*)x, (float4*)out, cnt,
                                             n4, n, x, out);
}

// Round 2
// 74.629 us; speedup vs baseline: 1.3183x; 1.3183x over previous
//
#include <hip/hip_runtime.h>

// HistogramEqualization: reference collapses to out = x * hist[1]/(N - hist[0])
// because jnp.interp(x in [0,1], arange(256), cdfn) only uses cdfn[0..1] and
// cdfn[0] == 0 (cdf.min() == cdf[0]).
//
// Kernel 1: count bin0 (x < 1/256) and bin1 (1/256 <= x < 2/256) exactly.
//   8 independent float4 loads in flight per wave (latency-bound fix, R1).
// Kernel 2: scale elementwise, 4-way unrolled.

__global__ __launch_bounds__(256) void histeq_count(const float4* __restrict__ x4,
                                                    unsigned long long* __restrict__ cnt,
                                                    int n4, const float* __restrict__ x,
                                                    int n) {
    unsigned int c0 = 0, c1 = 0;
    const int tid = blockIdx.x * blockDim.x + threadIdx.x;
    const int stride = gridDim.x * blockDim.x;

    int i = tid;
    // 8-way: 8 independent loads in flight per iteration
    for (; i + 7 * stride < n4; i += 8 * stride) {
        float4 v[8];
#pragma unroll
        for (int k = 0; k < 8; ++k) v[k] = x4[i + k * stride];
#pragma unroll
        for (int k = 0; k < 8; ++k) {
            int b0 = (int)(v[k].x * 256.0f);
            int b1 = (int)(v[k].y * 256.0f);
            int b2 = (int)(v[k].z * 256.0f);
            int b3 = (int)(v[k].w * 256.0f);
            c0 += (unsigned)(b0 == 0) + (unsigned)(b1 == 0) + (unsigned)(b2 == 0) + (unsigned)(b3 == 0);
            c1 += (unsigned)(b0 == 1) + (unsigned)(b1 == 1) + (unsigned)(b2 == 1) + (unsigned)(b3 == 1);
        }
    }
    for (; i < n4; i += stride) {
        float4 v = x4[i];
        int b0 = (int)(v.x * 256.0f);
        int b1 = (int)(v.y * 256.0f);
        int b2 = (int)(v.z * 256.0f);
        int b3 = (int)(v.w * 256.0f);
        c0 += (unsigned)(b0 == 0) + (unsigned)(b1 == 0) + (unsigned)(b2 == 0) + (unsigned)(b3 == 0);
        c1 += (unsigned)(b0 == 1) + (unsigned)(b1 == 1) + (unsigned)(b2 == 1) + (unsigned)(b3 == 1);
    }
    // scalar tail (n not multiple of 4) handled by one thread
    if (blockIdx.x == 0 && threadIdx.x == 0) {
        for (int j = n4 * 4; j < n; ++j) {
            int b = (int)(x[j] * 256.0f);
            c0 += (unsigned)(b == 0);
            c1 += (unsigned)(b == 1);
        }
    }
    // wave-64 butterfly reduce
#pragma unroll
    for (int off = 32; off > 0; off >>= 1) {
        c0 += __shfl_down(c0, off, 64);
        c1 += __shfl_down(c1, off, 64);
    }
    __shared__ unsigned int sm0[4], sm1[4];
    int lane = threadIdx.x & 63;
    int wid = threadIdx.x >> 6;
    if (lane == 0) { sm0[wid] = c0; sm1[wid] = c1; }
    __syncthreads();
    if (threadIdx.x == 0) {
        unsigned long long t0 = sm0[0] + sm0[1] + sm0[2] + sm0[3];
        unsigned long long t1 = sm1[0] + sm1[1] + sm1[2] + sm1[3];
        atomicAdd(cnt, t0 | (t1 << 32));  // one same-line atomic per block
    }
}

__global__ __launch_bounds__(256) void histeq_apply(const float4* __restrict__ x4,
                                                    float4* __restrict__ out4,
                                                    const unsigned long long* __restrict__ cnt,
                                                    int n4, int n_total,
                                                    const float* __restrict__ x,
                                                    float* __restrict__ out) {
    __shared__ float s_scale;
    if (threadIdx.x == 0) {
        unsigned long long c = *cnt;
        double h0 = (double)(unsigned int)(c & 0xFFFFFFFFull);
        double h1 = (double)(unsigned int)(c >> 32);
        s_scale = (float)(h1 / ((double)n_total - h0));
    }
    __syncthreads();
    const float s = s_scale;
    const int tid = blockIdx.x * blockDim.x + threadIdx.x;
    const int stride = gridDim.x * blockDim.x;

    int i = tid;
    for (; i + 3 * stride < n4; i += 4 * stride) {
        float4 v[4];
#pragma unroll
        for (int k = 0; k < 4; ++k) v[k] = x4[i + k * stride];
#pragma unroll
        for (int k = 0; k < 4; ++k) {
            float4 o;
            o.x = v[k].x * s;
            o.y = v[k].y * s;
            o.z = v[k].z * s;
            o.w = v[k].w * s;
            out4[i + k * stride] = o;
        }
    }
    for (; i < n4; i += stride) {
        float4 v = x4[i];
        float4 o;
        o.x = v.x * s;
        o.y = v.y * s;
        o.z = v.z * s;
        o.w = v.w * s;
        out4[i] = o;
    }
    if (blockIdx.x == 0 && threadIdx.x == 0) {
        for (int j = n4 * 4; j < n_total; ++j) out[j] = x[j] * s;
    }
}

extern "C" void kernel_launch(void* const* d_in, const int* in_sizes, int n_in,
                              void* d_out, int out_size, void* d_ws, size_t ws_size,
                              hipStream_t stream) {
    const float* x = (const float*)d_in[0];
    float* out = (float*)d_out;
    int n = in_sizes[0];
    int n4 = n >> 2;
    unsigned long long* cnt = (unsigned long long*)d_ws;

    hipMemsetAsync(cnt, 0, sizeof(unsigned long long), stream);

    const int block = 256;
    int grid = 2048;
    int need = (n4 + block - 1) / block;
    if (grid > need) grid = need;
    if (grid < 1) grid = 1;

    histeq_count<<<grid, block, 0, stream>>>((const float4*)x, cnt, n4, x, n);
    histeq_apply<<<grid, block, 0, stream>>>((const float4*)x, (float4*)out, cnt,
                                             n4, n, x, out);
}

// Round 3
// 58.655 us; speedup vs baseline: 1.6773x; 1.2723x over previous
//
#include <hip/hip_runtime.h>

// HistogramEqualization: reference collapses to out = x * hist[1]/(N - hist[0])
// because jnp.interp(x in [0,1], arange(256), cdfn) only uses cdfn[0..1] and
// cdfn[0] == 0 (cdf.min() == cdf[0]).
//
// R2: removed hipMemsetAsync (its 8-byte fillBufferAligned dispatch cost 57 µs
// per graph replay!). Count kernel writes atomic-free per-block partials to
// d_ws (each block overwrites its slot -> no init needed); apply kernel
// reduces the partials per-block (cheap, L2) then scales.

__global__ __launch_bounds__(256) void histeq_count(const float4* __restrict__ x4,
                                                    unsigned long long* __restrict__ partials,
                                                    int n4, const float* __restrict__ x,
                                                    int n) {
    unsigned int c0 = 0, c1 = 0;
    const int tid = blockIdx.x * blockDim.x + threadIdx.x;
    const int stride = gridDim.x * blockDim.x;

    int i = tid;
    // 8-way: 8 independent loads in flight per iteration (latency-bound fix, R1)
    for (; i + 7 * stride < n4; i += 8 * stride) {
        float4 v[8];
#pragma unroll
        for (int k = 0; k < 8; ++k) v[k] = x4[i + k * stride];
#pragma unroll
        for (int k = 0; k < 8; ++k) {
            int b0 = (int)(v[k].x * 256.0f);
            int b1 = (int)(v[k].y * 256.0f);
            int b2 = (int)(v[k].z * 256.0f);
            int b3 = (int)(v[k].w * 256.0f);
            c0 += (unsigned)(b0 == 0) + (unsigned)(b1 == 0) + (unsigned)(b2 == 0) + (unsigned)(b3 == 0);
            c1 += (unsigned)(b0 == 1) + (unsigned)(b1 == 1) + (unsigned)(b2 == 1) + (unsigned)(b3 == 1);
        }
    }
    for (; i < n4; i += stride) {
        float4 v = x4[i];
        int b0 = (int)(v.x * 256.0f);
        int b1 = (int)(v.y * 256.0f);
        int b2 = (int)(v.z * 256.0f);
        int b3 = (int)(v.w * 256.0f);
        c0 += (unsigned)(b0 == 0) + (unsigned)(b1 == 0) + (unsigned)(b2 == 0) + (unsigned)(b3 == 0);
        c1 += (unsigned)(b0 == 1) + (unsigned)(b1 == 1) + (unsigned)(b2 == 1) + (unsigned)(b3 == 1);
    }
    // scalar tail (n not multiple of 4) handled by one thread
    if (blockIdx.x == 0 && threadIdx.x == 0) {
        for (int j = n4 * 4; j < n; ++j) {
            int b = (int)(x[j] * 256.0f);
            c0 += (unsigned)(b == 0);
            c1 += (unsigned)(b == 1);
        }
    }
    // wave-64 butterfly reduce
#pragma unroll
    for (int off = 32; off > 0; off >>= 1) {
        c0 += __shfl_down(c0, off, 64);
        c1 += __shfl_down(c1, off, 64);
    }
    __shared__ unsigned int sm0[4], sm1[4];
    int lane = threadIdx.x & 63;
    int wid = threadIdx.x >> 6;
    if (lane == 0) { sm0[wid] = c0; sm1[wid] = c1; }
    __syncthreads();
    if (threadIdx.x == 0) {
        unsigned long long t0 = sm0[0] + sm0[1] + sm0[2] + sm0[3];
        unsigned long long t1 = sm1[0] + sm1[1] + sm1[2] + sm1[3];
        partials[blockIdx.x] = t0 | (t1 << 32);  // plain store, no atomic, no init
    }
}

__global__ __launch_bounds__(256) void histeq_apply(const float4* __restrict__ x4,
                                                    float4* __restrict__ out4,
                                                    const unsigned long long* __restrict__ partials,
                                                    int nparts,
                                                    int n4, int n_total,
                                                    const float* __restrict__ x,
                                                    float* __restrict__ out) {
    // per-block reduce of the count partials (L2-resident, ~16 KB)
    unsigned int c0 = 0, c1 = 0;
    for (int j = threadIdx.x; j < nparts; j += blockDim.x) {
        unsigned long long p = partials[j];
        c0 += (unsigned int)(p & 0xFFFFFFFFull);
        c1 += (unsigned int)(p >> 32);
    }
#pragma unroll
    for (int off = 32; off > 0; off >>= 1) {
        c0 += __shfl_down(c0, off, 64);
        c1 += __shfl_down(c1, off, 64);
    }
    __shared__ unsigned int sm0[4], sm1[4];
    __shared__ float s_scale;
    int lane = threadIdx.x & 63;
    int wid = threadIdx.x >> 6;
    if (lane == 0) { sm0[wid] = c0; sm1[wid] = c1; }
    __syncthreads();
    if (threadIdx.x == 0) {
        double h0 = (double)(sm0[0] + sm0[1] + sm0[2] + sm0[3]);
        double h1 = (double)(sm1[0] + sm1[1] + sm1[2] + sm1[3]);
        s_scale = (float)(h1 / ((double)n_total - h0));
    }
    __syncthreads();
    const float s = s_scale;
    const int tid = blockIdx.x * blockDim.x + threadIdx.x;
    const int stride = gridDim.x * blockDim.x;

    int i = tid;
    for (; i + 3 * stride < n4; i += 4 * stride) {
        float4 v[4];
#pragma unroll
        for (int k = 0; k < 4; ++k) v[k] = x4[i + k * stride];
#pragma unroll
        for (int k = 0; k < 4; ++k) {
            float4 o;
            o.x = v[k].x * s;
            o.y = v[k].y * s;
            o.z = v[k].z * s;
            o.w = v[k].w * s;
            out4[i + k * stride] = o;
        }
    }
    for (; i < n4; i += stride) {
        float4 v = x4[i];
        float4 o;
        o.x = v.x * s;
        o.y = v.y * s;
        o.z = v.z * s;
        o.w = v.w * s;
        out4[i] = o;
    }
    if (blockIdx.x == 0 && threadIdx.x == 0) {
        for (int j = n4 * 4; j < n_total; ++j) out[j] = x[j] * s;
    }
}

extern "C" void kernel_launch(void* const* d_in, const int* in_sizes, int n_in,
                              void* d_out, int out_size, void* d_ws, size_t ws_size,
                              hipStream_t stream) {
    const float* x = (const float*)d_in[0];
    float* out = (float*)d_out;
    int n = in_sizes[0];
    int n4 = n >> 2;
    unsigned long long* partials = (unsigned long long*)d_ws;

    const int block = 256;
    int grid = 2048;
    int need = (n4 + block - 1) / block;
    if (grid > need) grid = need;
    if (grid < 1) grid = 1;

    histeq_count<<<grid, block, 0, stream>>>((const float4*)x, partials, n4, x, n);
    histeq_apply<<<grid, block, 0, stream>>>((const float4*)x, (float4*)out, partials,
                                             grid, n4, n, x, out);
}